// Round 14
// baseline (113.103 us; speedup 1.0000x reference)
//
#include <hip/hip_runtime.h>
#include <hip/hip_fp16.h>

#define CH 16
#define NPIX (4 * 512 * 512)
#define NBINS 4096        // 64x64 bins of 16x16 layer1 texels
#define NBLK_SORT 256     // sort-pass blocks
#define PPB (NPIX / NBLK_SORT)   // 4096 pixels per sort block
#define NILV 2720         // interleave blocks (1392640 texels / 512)

// Native clang vector for nontemporal builtins (HIP_vector_type not accepted).
typedef float vfloat4 __attribute__((ext_vector_type(4)));

// ---------------------------------------------------------------------------
// Binning: bin = 16x16-texel tile at layer1 (1024^2) resolution.
// ---------------------------------------------------------------------------
__device__ __forceinline__ int bin_of(float xv, float yv) {
  int bx = min(max((int)(xv * 1023.0f), 0), 1023) >> 4;
  int by = min(max((int)(yv * 1023.0f), 0), 1023) >> 4;
  return (by << 6) + bx;
}

// ---------------------------------------------------------------------------
// Fused front-end: blocks [0, NILV) repack layers f32->fp16 interleaved via
// LDS transpose; blocks [NILV, NILV+256) compute the per-sort-block histogram.
// ---------------------------------------------------------------------------
__global__ __launch_bounds__(256) void ilv_hist_kernel(
    const float* __restrict__ l1, const float* __restrict__ l2,
    const float* __restrict__ l3, const float* __restrict__ l4,
    __half* __restrict__ w1, __half* __restrict__ w2,
    __half* __restrict__ w3, __half* __restrict__ w4,
    const float2* __restrict__ x, unsigned* __restrict__ hist) {
  __shared__ unsigned s_lds[CH * 258];  // 16.5 KB; also holds hist[4096]
  int b = blockIdx.x, t = threadIdx.x;
  if (b >= NILV) {
    // ---- histogram path ----
    int blk = b - NILV;
#pragma unroll
    for (int i = 0; i < NBINS / 256; ++i) s_lds[i * 256 + t] = 0;
    __syncthreads();
    int base = blk * PPB;
#pragma unroll 4
    for (int c = 0; c < PPB / 256; ++c) {
      float2 g = x[base + c * 256 + t];
      atomicAdd(&s_lds[bin_of(g.x, g.y)], 1u);
    }
    __syncthreads();
#pragma unroll
    for (int i = 0; i < NBINS / 256; ++i)
      hist[(size_t)blk * NBINS + i * 256 + t] = s_lds[i * 256 + t];
    return;
  }
  // ---- interleave path: 512 texels/block, LDS transpose ----
  const float* src; __half* dst; int HW; size_t tb;
  if (b < 2048)      { src = l1; dst = w1; HW = 1048576; tb = (size_t)b * 512; }
  else if (b < 2560) { src = l2; dst = w2; HW = 262144;  tb = (size_t)(b - 2048) * 512; }
  else if (b < 2688) { src = l3; dst = w3; HW = 65536;   tb = (size_t)(b - 2560) * 512; }
  else               { src = l4; dst = w4; HW = 16384;   tb = (size_t)(b - 2688) * 512; }
  int lane = t & 63, cg = t >> 6;
#pragma unroll
  for (int j = 0; j < 4; ++j) {
    int c = cg * 4 + j;
    const vfloat4* s4 = (const vfloat4*)(src + (size_t)c * HW + tb);
#pragma unroll
    for (int half_ = 0; half_ < 2; ++half_) {
      vfloat4 v = __builtin_nontemporal_load(&s4[half_ * 64 + lane]);
      unsigned h0 = __half_as_ushort(__float2half(v.x));
      unsigned h1 = __half_as_ushort(__float2half(v.y));
      unsigned h2 = __half_as_ushort(__float2half(v.z));
      unsigned h3 = __half_as_ushort(__float2half(v.w));
      s_lds[c * 258 + half_ * 128 + lane * 2 + 0] = h0 | (h1 << 16);
      s_lds[c * 258 + half_ * 128 + lane * 2 + 1] = h2 | (h3 << 16);
    }
  }
  __syncthreads();
#pragma unroll
  for (int q = 0; q < 2; ++q) {
    int tt = t + q * 256;
    int idx = tt >> 1, sh = (tt & 1) * 16;
    unsigned o[8];
#pragma unroll
    for (int k = 0; k < 8; ++k) {
      unsigned lo = (s_lds[(2 * k + 0) * 258 + idx] >> sh) & 0xffffu;
      unsigned hi = (s_lds[(2 * k + 1) * 258 + idx] >> sh) & 0xffffu;
      o[k] = lo | (hi << 16);
    }
    uint4* d = (uint4*)(dst + (tb + tt) * CH);
    d[0] = make_uint4(o[0], o[1], o[2], o[3]);
    d[1] = make_uint4(o[4], o[5], o[6], o[7]);
  }
}

// Per-bin column scan over the 256 sort-blocks.
__global__ __launch_bounds__(256) void colscan2_kernel(
    unsigned* __restrict__ hist, unsigned* __restrict__ totals) {
  int bin = blockIdx.x * 256 + threadIdx.x;
  unsigned run = 0;
  for (int k = 0; k < NBLK_SORT; ++k) {
    size_t idx = (size_t)k * NBINS + bin;
    unsigned v = hist[idx];
    hist[idx] = run;
    run += v;
  }
  totals[bin] = run;
}

// Exclusive scan of 4096 totals -> binbase (one block, 1024 threads).
__global__ __launch_bounds__(1024) void scan_kernel(
    const unsigned* __restrict__ counts, unsigned* __restrict__ cursor) {
  __shared__ unsigned part[1024];
  int t = threadIdx.x;
  unsigned c0 = counts[4 * t + 0], c1 = counts[4 * t + 1];
  unsigned c2 = counts[4 * t + 2], c3 = counts[4 * t + 3];
  part[t] = c0 + c1 + c2 + c3;
  __syncthreads();
  for (int off = 1; off < 1024; off <<= 1) {
    unsigned v = (t >= off) ? part[t - off] : 0u;
    __syncthreads();
    part[t] += v;
    __syncthreads();
  }
  unsigned base = (t > 0) ? part[t - 1] : 0u;  // exclusive
  cursor[4 * t + 0] = base;
  cursor[4 * t + 1] = base + c0;
  cursor[4 * t + 2] = base + c0 + c1;
  cursor[4 * t + 3] = base + c0 + c1 + c2;
}

// Scatter 8-byte records {(qv<<16)|qu, p} with LDS cursors. Mask NOT stored
// (applied in unscatter where msk[p] is a coalesced read).
__global__ __launch_bounds__(256) void scatter3_kernel(
    const float2* __restrict__ x, const unsigned* __restrict__ hist,
    const unsigned* __restrict__ binbase, uint2* __restrict__ pixrec) {
  __shared__ unsigned cur[NBINS];
  int tid = threadIdx.x, blk = blockIdx.x;
#pragma unroll
  for (int i = 0; i < NBINS / 256; ++i)
    cur[i * 256 + tid] = hist[(size_t)blk * NBINS + i * 256 + tid] +
                         binbase[i * 256 + tid];
  __syncthreads();
  int base = blk * PPB;
#pragma unroll 4
  for (int c = 0; c < PPB / 256; ++c) {
    int p = base + c * 256 + tid;
    float2 g = x[p];
    unsigned qu = min((unsigned)(g.x * 65536.0f), 65535u);
    unsigned qv = min((unsigned)(g.y * 65536.0f), 65535u);
    unsigned i = atomicAdd(&cur[bin_of(g.x, g.y)], 1u);
    pixrec[i] = make_uint2((qv << 16) | qu, (unsigned)p);
  }
}

// ---------------------------------------------------------------------------
// Per-layer bilinear tap, shared validity (c00..c11), ix = u*(W-1) shortcut.
// ---------------------------------------------------------------------------
__device__ __forceinline__ void sample_layer(const uint4* __restrict__ base,
                                             int W, float u, float v, int h,
                                             float c00, float c01, float c10,
                                             float c11, float acc[8]) {
  float ix = u * (float)(W - 1);
  float iy = v * (float)(W - 1);
  float fx = floorf(ix), fy = floorf(iy);
  float wx1 = ix - fx, wy1 = iy - fy;
  float wx0 = 1.0f - wx1, wy0 = 1.0f - wy1;
  int x0 = min(max((int)fx, 0), W - 1);
  int x1 = min(x0 + 1, W - 1);
  int y0 = min(max((int)fy, 0), W - 1);
  int y1 = min(y0 + 1, W - 1);
  union { uint4 u4; __half2 hh[4]; } a00, a01, a10, a11;
  a00.u4 = base[((size_t)y0 * W + x0) * 2 + h];
  a01.u4 = base[((size_t)y0 * W + x1) * 2 + h];
  a10.u4 = base[((size_t)y1 * W + x0) * 2 + h];
  a11.u4 = base[((size_t)y1 * W + x1) * 2 + h];
  __half2 w00h = __float2half2_rn(wy0 * wx0 * c00);
  __half2 w01h = __float2half2_rn(wy0 * wx1 * c01);
  __half2 w10h = __float2half2_rn(wy1 * wx0 * c10);
  __half2 w11h = __float2half2_rn(wy1 * wx1 * c11);
#pragma unroll
  for (int i = 0; i < 4; ++i) {
    __half2 s = __hmul2(a00.hh[i], w00h);
    s = __hfma2(a01.hh[i], w01h, s);
    s = __hfma2(a10.hh[i], w10h, s);
    s = __hfma2(a11.hh[i], w11h, s);
    float2 f = __half22float2(s);
    acc[2 * i + 0] += f.x;
    acc[2 * i + 1] += f.y;
  }
}

// Gather in bin order, 2 threads/pixel, 8B records, no in-block sort
// (proven neutral R5/R12 -> gather is latency/issue-bound, keep it lean).
__global__ __launch_bounds__(256) void gather_binned5_kernel(
    const uint2* __restrict__ pixrec,
    const __half* __restrict__ t1, const __half* __restrict__ t2,
    const __half* __restrict__ t3, const __half* __restrict__ t4,
    __half* __restrict__ ws2) {
  // 8192 blocks; XCD-chunked swizzle -> 1024-block contiguous chunks.
  int bid = blockIdx.x;
  int swz = (bid & 7) * 1024 + (bid >> 3);
  int g = swz * 256 + threadIdx.x;
  int i = g >> 1;        // pixel slot in bin order
  int h = g & 1;         // channel half (0: ch0-7, 1: ch8-15)
  uint2 r = pixrec[i];
  float u = ((float)(r.x & 0xffffu) + 0.5f) * (1.0f / 65536.0f);
  float v = ((float)(r.x >> 16) + 0.5f) * (1.0f / 65536.0f);
  unsigned p = r.y;
  // Shared validity from layer1's unclamped indices (u,v in [0,1) -> all 1,
  // but keep the reference's zeros-padding semantics).
  float fx = floorf(u * 1023.0f), fy = floorf(v * 1023.0f);
  float vx0 = (fx >= 0.0f && fx <= 1023.0f) ? 1.0f : 0.0f;
  float vx1 = (fx + 1.0f >= 0.0f && fx + 1.0f <= 1023.0f) ? 1.0f : 0.0f;
  float vy0 = (fy >= 0.0f && fy <= 1023.0f) ? 1.0f : 0.0f;
  float vy1 = (fy + 1.0f >= 0.0f && fy + 1.0f <= 1023.0f) ? 1.0f : 0.0f;
  float c00 = vy0 * vx0, c01 = vy0 * vx1, c10 = vy1 * vx0, c11 = vy1 * vx1;
  float acc[8];
#pragma unroll
  for (int c = 0; c < 8; ++c) acc[c] = 0.0f;
  sample_layer((const uint4*)t1, 1024, u, v, h, c00, c01, c10, c11, acc);
  sample_layer((const uint4*)t2, 512, u, v, h, c00, c01, c10, c11, acc);
  sample_layer((const uint4*)t3, 256, u, v, h, c00, c01, c10, c11, acc);
  sample_layer((const uint4*)t4, 128, u, v, h, c00, c01, c10, c11, acc);
  union { __half2 hh[4]; uint4 u4; } o;
#pragma unroll
  for (int c = 0; c < 4; ++c)
    o.hh[c] = __floats2half2_rn(acc[2 * c], acc[2 * c + 1]);
  ((uint4*)(ws2 + (size_t)p * CH))[h] = o.u4;
}

// Unscatter fp16 ws2[p][16] * msk[p] -> f32 out[B][C][Ho][Wo]. 4 px/thread.
__global__ __launch_bounds__(256) void unscatter16m_kernel(
    const __half* __restrict__ ws2, const float* __restrict__ msk,
    float* __restrict__ out) {
  int t = blockIdx.x * blockDim.x + threadIdx.x;  // [0, NPIX/4)
  int p0 = t * 4;
  int wo = p0 & 511, ho = (p0 >> 9) & 511, b = p0 >> 18;
  float4 m4 = ((const float4*)msk)[t];
  const uint4* s = (const uint4*)ws2;
  union { uint4 u[2]; __half2 h[8]; } v[4];
#pragma unroll
  for (int j = 0; j < 4; ++j) {
    v[j].u[0] = s[(size_t)(p0 + j) * 2 + 0];
    v[j].u[1] = s[(size_t)(p0 + j) * 2 + 1];
  }
  size_t obase = (size_t)b * (CH * 262144) + (size_t)ho * 512 + wo;
#pragma unroll
  for (int ch = 0; ch < CH; ++ch) {
    vfloat4 o;
    o.x = __half2float(((ch & 1) ? __high2half(v[0].h[ch >> 1]) : __low2half(v[0].h[ch >> 1]))) * m4.x;
    o.y = __half2float(((ch & 1) ? __high2half(v[1].h[ch >> 1]) : __low2half(v[1].h[ch >> 1]))) * m4.y;
    o.z = __half2float(((ch & 1) ? __high2half(v[2].h[ch >> 1]) : __low2half(v[2].h[ch >> 1]))) * m4.z;
    o.w = __half2float(((ch & 1) ? __high2half(v[3].h[ch >> 1]) : __low2half(v[3].h[ch >> 1]))) * m4.w;
    __builtin_nontemporal_store(o, (vfloat4*)(out + obase + (size_t)ch * 262144));
  }
}

// ---------------------------------------------------------------------------
// Fallback path kernels (ws too small for the binned pipeline).
// ---------------------------------------------------------------------------
__global__ __launch_bounds__(256) void interleave_lds2_kernel(
    const float* __restrict__ l1, const float* __restrict__ l2,
    const float* __restrict__ l3, const float* __restrict__ l4,
    __half* __restrict__ w1, __half* __restrict__ w2,
    __half* __restrict__ w3, __half* __restrict__ w4) {
  __shared__ unsigned lds_u[CH][258];
  int b = blockIdx.x;
  const float* src; __half* dst; int HW; size_t tb;
  if (b < 2048)      { src = l1; dst = w1; HW = 1048576; tb = (size_t)b * 512; }
  else if (b < 2560) { src = l2; dst = w2; HW = 262144;  tb = (size_t)(b - 2048) * 512; }
  else if (b < 2688) { src = l3; dst = w3; HW = 65536;   tb = (size_t)(b - 2560) * 512; }
  else               { src = l4; dst = w4; HW = 16384;   tb = (size_t)(b - 2688) * 512; }
  int t = threadIdx.x, lane = t & 63, cg = t >> 6;
#pragma unroll
  for (int j = 0; j < 4; ++j) {
    int c = cg * 4 + j;
    const vfloat4* s4 = (const vfloat4*)(src + (size_t)c * HW + tb);
#pragma unroll
    for (int half_ = 0; half_ < 2; ++half_) {
      vfloat4 v = __builtin_nontemporal_load(&s4[half_ * 64 + lane]);
      unsigned h0 = __half_as_ushort(__float2half(v.x));
      unsigned h1 = __half_as_ushort(__float2half(v.y));
      unsigned h2 = __half_as_ushort(__float2half(v.z));
      unsigned h3 = __half_as_ushort(__float2half(v.w));
      lds_u[c][half_ * 128 + lane * 2 + 0] = h0 | (h1 << 16);
      lds_u[c][half_ * 128 + lane * 2 + 1] = h2 | (h3 << 16);
    }
  }
  __syncthreads();
#pragma unroll
  for (int q = 0; q < 2; ++q) {
    int tt = t + q * 256;
    int idx = tt >> 1, sh = (tt & 1) * 16;
    unsigned o[8];
#pragma unroll
    for (int k = 0; k < 8; ++k) {
      unsigned lo = (lds_u[2 * k + 0][idx] >> sh) & 0xffffu;
      unsigned hi = (lds_u[2 * k + 1][idx] >> sh) & 0xffffu;
      o[k] = lo | (hi << 16);
    }
    uint4* d = (uint4*)(dst + (tb + tt) * CH);
    d[0] = make_uint4(o[0], o[1], o[2], o[3]);
    d[1] = make_uint4(o[4], o[5], o[6], o[7]);
  }
}

__device__ __forceinline__ void corner_fma(const __half* __restrict__ t,
                                           size_t texel, float w, float acc[CH]) {
  const uint4* q = (const uint4*)(t + texel * CH);
  union { uint4 u; __half2 h[4]; } a, b;
  a.u = q[0];
  b.u = q[1];
#pragma unroll
  for (int i = 0; i < 4; ++i) {
    float2 f = __half22float2(a.h[i]);
    acc[2 * i + 0] = fmaf(f.x, w, acc[2 * i + 0]);
    acc[2 * i + 1] = fmaf(f.y, w, acc[2 * i + 1]);
  }
#pragma unroll
  for (int i = 0; i < 4; ++i) {
    float2 f = __half22float2(b.h[i]);
    acc[8 + 2 * i + 0] = fmaf(f.x, w, acc[8 + 2 * i + 0]);
    acc[8 + 2 * i + 1] = fmaf(f.y, w, acc[8 + 2 * i + 1]);
  }
}

__device__ __forceinline__ void sample_hwc16(const __half* __restrict__ t, int W,
                                             float gx, float gy, float acc[CH]) {
  const float W1 = (float)(W - 1);
  float ix = (gx + 1.0f) * 0.5f * W1;
  float iy = (gy + 1.0f) * 0.5f * W1;
  float ix0f = floorf(ix), iy0f = floorf(iy);
  float wx1 = ix - ix0f, wy1 = iy - iy0f;
  float wx0 = 1.0f - wx1, wy0 = 1.0f - wy1;
  float ix1f = ix0f + 1.0f, iy1f = iy0f + 1.0f;
  float vx0 = (ix0f >= 0.0f && ix0f <= W1) ? 1.0f : 0.0f;
  float vx1 = (ix1f >= 0.0f && ix1f <= W1) ? 1.0f : 0.0f;
  float vy0 = (iy0f >= 0.0f && iy0f <= W1) ? 1.0f : 0.0f;
  float vy1 = (iy1f >= 0.0f && iy1f <= W1) ? 1.0f : 0.0f;
  int x0 = min(max((int)ix0f, 0), W - 1);
  int x1 = min(max((int)ix1f, 0), W - 1);
  int y0 = min(max((int)iy0f, 0), W - 1);
  int y1 = min(max((int)iy1f, 0), W - 1);
  float w00 = wy0 * wx0 * vy0 * vx0;
  float w01 = wy0 * wx1 * vy0 * vx1;
  float w10 = wy1 * wx0 * vy1 * vx0;
  float w11 = wy1 * wx1 * vy1 * vx1;
  corner_fma(t, (size_t)y0 * W + x0, w00, acc);
  corner_fma(t, (size_t)y0 * W + x1, w01, acc);
  corner_fma(t, (size_t)y1 * W + x0, w10, acc);
  corner_fma(t, (size_t)y1 * W + x1, w11, acc);
}

__global__ __launch_bounds__(256) void gather_hwc16_kernel(
    const float* __restrict__ x, const float* __restrict__ msk,
    const __half* __restrict__ t1, const __half* __restrict__ t2,
    const __half* __restrict__ t3, const __half* __restrict__ t4,
    float* __restrict__ out) {
  int p = blockIdx.x * blockDim.x + threadIdx.x;
  int wo = p & 511, ho = (p >> 9) & 511, b = p >> 18;
  float2 g = ((const float2*)x)[p];
  float gx = g.x * 2.0f - 1.0f;
  float gy = g.y * 2.0f - 1.0f;
  float m = msk[p];
  float acc[CH];
#pragma unroll
  for (int c = 0; c < CH; ++c) acc[c] = 0.0f;
  sample_hwc16(t1, 1024, gx, gy, acc);
  sample_hwc16(t2, 512, gx, gy, acc);
  sample_hwc16(t3, 256, gx, gy, acc);
  sample_hwc16(t4, 128, gx, gy, acc);
  size_t obase = (size_t)b * (CH * 262144) + (size_t)ho * 512 + wo;
#pragma unroll
  for (int c = 0; c < CH; ++c) out[obase + (size_t)c * 262144] = acc[c] * m;
}

__device__ __forceinline__ void sample_chw(const float* __restrict__ t, int W,
                                           float gx, float gy, float acc[CH]) {
  const float W1 = (float)(W - 1);
  float ix = (gx + 1.0f) * 0.5f * W1;
  float iy = (gy + 1.0f) * 0.5f * W1;
  float ix0f = floorf(ix), iy0f = floorf(iy);
  float wx1 = ix - ix0f, wy1 = iy - iy0f;
  float wx0 = 1.0f - wx1, wy0 = 1.0f - wy1;
  float ix1f = ix0f + 1.0f, iy1f = iy0f + 1.0f;
  float vx0 = (ix0f >= 0.0f && ix0f <= W1) ? 1.0f : 0.0f;
  float vx1 = (ix1f >= 0.0f && ix1f <= W1) ? 1.0f : 0.0f;
  float vy0 = (iy0f >= 0.0f && iy0f <= W1) ? 1.0f : 0.0f;
  float vy1 = (iy1f >= 0.0f && iy1f <= W1) ? 1.0f : 0.0f;
  int x0 = min(max((int)ix0f, 0), W - 1);
  int x1 = min(max((int)ix1f, 0), W - 1);
  int y0 = min(max((int)iy0f, 0), W - 1);
  int y1 = min(max((int)iy1f, 0), W - 1);
  float w00 = wy0 * wx0 * vy0 * vx0;
  float w01 = wy0 * wx1 * vy0 * vx1;
  float w10 = wy1 * wx0 * vy1 * vx0;
  float w11 = wy1 * wx1 * vy1 * vx1;
  size_t HW = (size_t)W * W;
  const float* b00 = t + (size_t)y0 * W + x0;
  const float* b01 = t + (size_t)y0 * W + x1;
  const float* b10 = t + (size_t)y1 * W + x0;
  const float* b11 = t + (size_t)y1 * W + x1;
#pragma unroll
  for (int c = 0; c < CH; ++c) {
    float v00 = b00[c * HW], v01 = b01[c * HW], v10 = b10[c * HW], v11 = b11[c * HW];
    acc[c] = fmaf(v00, w00, fmaf(v01, w01, fmaf(v10, w10, fmaf(v11, w11, acc[c]))));
  }
}

__global__ __launch_bounds__(256) void gather_chw_kernel(
    const float* __restrict__ x, const float* __restrict__ msk,
    const float* __restrict__ l1, const float* __restrict__ l2,
    const float* __restrict__ l3, const float* __restrict__ l4,
    float* __restrict__ out) {
  int p = blockIdx.x * blockDim.x + threadIdx.x;
  int wo = p & 511, ho = (p >> 9) & 511, b = p >> 18;
  float2 g = ((const float2*)x)[p];
  float gx = g.x * 2.0f - 1.0f;
  float gy = g.y * 2.0f - 1.0f;
  float m = msk[p];
  float acc[CH];
#pragma unroll
  for (int c = 0; c < CH; ++c) acc[c] = 0.0f;
  sample_chw(l1, 1024, gx, gy, acc);
  sample_chw(l2, 512, gx, gy, acc);
  sample_chw(l3, 256, gx, gy, acc);
  sample_chw(l4, 128, gx, gy, acc);
  size_t obase = (size_t)b * (CH * 262144) + (size_t)ho * 512 + wo;
#pragma unroll
  for (int c = 0; c < CH; ++c) out[obase + (size_t)c * 262144] = acc[c] * m;
}

extern "C" void kernel_launch(void* const* d_in, const int* in_sizes, int n_in,
                              void* d_out, int out_size, void* d_ws, size_t ws_size,
                              hipStream_t stream) {
  const float* x   = (const float*)d_in[0];
  const float* msk = (const float*)d_in[1];
  const float* l1  = (const float*)d_in[2];
  const float* l2  = (const float*)d_in[3];
  const float* l3  = (const float*)d_in[4];
  const float* l4  = (const float*)d_in[5];
  float* out = (float*)d_out;

  const size_t n_texel = 1048576 + 262144 + 65536 + 16384;      // 1392640
  const size_t tex_bytes = n_texel * CH * sizeof(__half);        // ~44.6 MB
  const size_t ws2_bytes = (size_t)NPIX * CH * sizeof(__half);   // 32 MB
  const size_t rec_bytes = (size_t)NPIX * sizeof(uint2);         // 8 MB
  const size_t need_bin  = ws2_bytes + tex_bytes + rec_bytes;
  const size_t need_f16  = tex_bytes;

  if (ws_size >= need_bin) {
    char* base = (char*)d_ws;
    __half* ws2    = (__half*)base;
    __half* w1     = (__half*)(base + ws2_bytes);
    __half* w2     = w1 + (size_t)1048576 * CH;
    __half* w3     = w2 + (size_t)262144 * CH;
    __half* w4     = w3 + (size_t)65536 * CH;
    uint2*  pixrec = (uint2*)(base + ws2_bytes + tex_bytes);
    // Sort metadata aliases into ws2 (dead once gather starts writing ws2):
    unsigned* hist    = (unsigned*)base;                          // 4 MB
    unsigned* totals  = hist + (size_t)NBLK_SORT * NBINS;         // 16 KB
    unsigned* binbase = totals + NBINS;                           // 16 KB

    ilv_hist_kernel<<<NILV + NBLK_SORT, 256, 0, stream>>>(
        l1, l2, l3, l4, w1, w2, w3, w4, (const float2*)x, hist);
    colscan2_kernel<<<NBINS / 256, 256, 0, stream>>>(hist, totals);
    scan_kernel<<<1, 1024, 0, stream>>>(totals, binbase);
    scatter3_kernel<<<NBLK_SORT, 256, 0, stream>>>(
        (const float2*)x, hist, binbase, pixrec);
    gather_binned5_kernel<<<NPIX * 2 / 256, 256, 0, stream>>>(
        pixrec, w1, w2, w3, w4, ws2);
    unscatter16m_kernel<<<NPIX / 4 / 256, 256, 0, stream>>>(ws2, msk, out);
  } else if (ws_size >= need_f16) {
    __half* w1 = (__half*)d_ws;
    __half* w2 = w1 + (size_t)1048576 * CH;
    __half* w3 = w2 + (size_t)262144 * CH;
    __half* w4 = w3 + (size_t)65536 * CH;
    interleave_lds2_kernel<<<(int)(n_texel / 512), 256, 0, stream>>>(
        l1, l2, l3, l4, w1, w2, w3, w4);
    gather_hwc16_kernel<<<NPIX / 256, 256, 0, stream>>>(x, msk, w1, w2, w3, w4, out);
  } else {
    gather_chw_kernel<<<NPIX / 256, 256, 0, stream>>>(x, msk, l1, l2, l3, l4, out);
  }
}

// Round 15
// 107.701 us; speedup vs baseline: 1.0502x; 1.0502x over previous
//
#include <hip/hip_runtime.h>
#include <hip/hip_fp16.h>

#define CH 16
#define NPIX (4 * 512 * 512)
#define NBINS 4096        // 64x64 bins of 16x16 layer1 texels
#define NBLK_SORT 256     // sort-pass blocks
#define PPB (NPIX / NBLK_SORT)   // 4096 pixels per sort block
#define NILV 2720         // interleave blocks (1392640 texels / 512)

// Native clang vector for nontemporal builtins (HIP_vector_type not accepted).
typedef float vfloat4 __attribute__((ext_vector_type(4)));

// ---------------------------------------------------------------------------
// Binning: bin = 16x16-texel tile at layer1 (1024^2) resolution.
// ---------------------------------------------------------------------------
__device__ __forceinline__ int bin_of(float xv, float yv) {
  int bx = min(max((int)(xv * 1023.0f), 0), 1023) >> 4;
  int by = min(max((int)(yv * 1023.0f), 0), 1023) >> 4;
  return (by << 6) + bx;
}

// ---------------------------------------------------------------------------
// Fused front-end: blocks [0, 256) compute the per-sort-block histogram
// (FIRST so they start immediately, no serialization tail); blocks
// [256, 256+NILV) repack layers f32->fp16 interleaved via LDS transpose.
// ---------------------------------------------------------------------------
__global__ __launch_bounds__(256) void ilv_hist_kernel(
    const float* __restrict__ l1, const float* __restrict__ l2,
    const float* __restrict__ l3, const float* __restrict__ l4,
    __half* __restrict__ w1, __half* __restrict__ w2,
    __half* __restrict__ w3, __half* __restrict__ w4,
    const float2* __restrict__ x, unsigned* __restrict__ hist) {
  __shared__ unsigned s_lds[CH * 258];  // 16.5 KB; also holds hist[4096]
  int b0 = blockIdx.x, t = threadIdx.x;
  if (b0 < NBLK_SORT) {
    // ---- histogram path ----
    int blk = b0;
#pragma unroll
    for (int i = 0; i < NBINS / 256; ++i) s_lds[i * 256 + t] = 0;
    __syncthreads();
    int base = blk * PPB;
#pragma unroll 4
    for (int c = 0; c < PPB / 256; ++c) {
      float2 g = x[base + c * 256 + t];
      atomicAdd(&s_lds[bin_of(g.x, g.y)], 1u);
    }
    __syncthreads();
#pragma unroll
    for (int i = 0; i < NBINS / 256; ++i)
      hist[(size_t)blk * NBINS + i * 256 + t] = s_lds[i * 256 + t];
    return;
  }
  // ---- interleave path: 512 texels/block, LDS transpose ----
  int b = b0 - NBLK_SORT;
  const float* src; __half* dst; int HW; size_t tb;
  if (b < 2048)      { src = l1; dst = w1; HW = 1048576; tb = (size_t)b * 512; }
  else if (b < 2560) { src = l2; dst = w2; HW = 262144;  tb = (size_t)(b - 2048) * 512; }
  else if (b < 2688) { src = l3; dst = w3; HW = 65536;   tb = (size_t)(b - 2560) * 512; }
  else               { src = l4; dst = w4; HW = 16384;   tb = (size_t)(b - 2688) * 512; }
  int lane = t & 63, cg = t >> 6;
#pragma unroll
  for (int j = 0; j < 4; ++j) {
    int c = cg * 4 + j;
    const vfloat4* s4 = (const vfloat4*)(src + (size_t)c * HW + tb);
#pragma unroll
    for (int half_ = 0; half_ < 2; ++half_) {
      vfloat4 v = __builtin_nontemporal_load(&s4[half_ * 64 + lane]);
      unsigned h0 = __half_as_ushort(__float2half(v.x));
      unsigned h1 = __half_as_ushort(__float2half(v.y));
      unsigned h2 = __half_as_ushort(__float2half(v.z));
      unsigned h3 = __half_as_ushort(__float2half(v.w));
      s_lds[c * 258 + half_ * 128 + lane * 2 + 0] = h0 | (h1 << 16);
      s_lds[c * 258 + half_ * 128 + lane * 2 + 1] = h2 | (h3 << 16);
    }
  }
  __syncthreads();
#pragma unroll
  for (int q = 0; q < 2; ++q) {
    int tt = t + q * 256;
    int idx = tt >> 1, sh = (tt & 1) * 16;
    unsigned o[8];
#pragma unroll
    for (int k = 0; k < 8; ++k) {
      unsigned lo = (s_lds[(2 * k + 0) * 258 + idx] >> sh) & 0xffffu;
      unsigned hi = (s_lds[(2 * k + 1) * 258 + idx] >> sh) & 0xffffu;
      o[k] = lo | (hi << 16);
    }
    uint4* d = (uint4*)(dst + (tb + tt) * CH);
    d[0] = make_uint4(o[0], o[1], o[2], o[3]);
    d[1] = make_uint4(o[4], o[5], o[6], o[7]);
  }
}

// Per-bin column scan over the 256 sort-blocks.
__global__ __launch_bounds__(256) void colscan2_kernel(
    unsigned* __restrict__ hist, unsigned* __restrict__ totals) {
  int bin = blockIdx.x * 256 + threadIdx.x;
  unsigned run = 0;
  for (int k = 0; k < NBLK_SORT; ++k) {
    size_t idx = (size_t)k * NBINS + bin;
    unsigned v = hist[idx];
    hist[idx] = run;
    run += v;
  }
  totals[bin] = run;
}

// Exclusive scan of 4096 totals -> binbase (one block, 1024 threads).
__global__ __launch_bounds__(1024) void scan_kernel(
    const unsigned* __restrict__ counts, unsigned* __restrict__ cursor) {
  __shared__ unsigned part[1024];
  int t = threadIdx.x;
  unsigned c0 = counts[4 * t + 0], c1 = counts[4 * t + 1];
  unsigned c2 = counts[4 * t + 2], c3 = counts[4 * t + 3];
  part[t] = c0 + c1 + c2 + c3;
  __syncthreads();
  for (int off = 1; off < 1024; off <<= 1) {
    unsigned v = (t >= off) ? part[t - off] : 0u;
    __syncthreads();
    part[t] += v;
    __syncthreads();
  }
  unsigned base = (t > 0) ? part[t - 1] : 0u;  // exclusive
  cursor[4 * t + 0] = base;
  cursor[4 * t + 1] = base + c0;
  cursor[4 * t + 2] = base + c0 + c1;
  cursor[4 * t + 3] = base + c0 + c1 + c2;
}

// Scatter float4 records {u, v, bits(p), mask} with LDS cursors
// (= hist rel-base + binbase). No global atomics.
__global__ __launch_bounds__(256) void scatter2_kernel(
    const float2* __restrict__ x, const float* __restrict__ msk,
    const unsigned* __restrict__ hist, const unsigned* __restrict__ binbase,
    float4* __restrict__ pixrec) {
  __shared__ unsigned cur[NBINS];
  int tid = threadIdx.x, blk = blockIdx.x;
#pragma unroll
  for (int i = 0; i < NBINS / 256; ++i)
    cur[i * 256 + tid] = hist[(size_t)blk * NBINS + i * 256 + tid] +
                         binbase[i * 256 + tid];
  __syncthreads();
  int base = blk * PPB;
#pragma unroll 4
  for (int c = 0; c < PPB / 256; ++c) {
    int p = base + c * 256 + tid;
    float2 g = x[p];
    float m = msk[p];
    unsigned i = atomicAdd(&cur[bin_of(g.x, g.y)], 1u);
    pixrec[i] = make_float4(g.x, g.y, __uint_as_float((unsigned)p), m);
  }
}

// Gather: 2 threads/pixel, ALL 16 corner loads issued up-front (4x per-thread
// MLP vs per-layer serialization) then all blends. VGPR ~100, no spill.
__global__ __launch_bounds__(256) void gather_binned6_kernel(
    const float4* __restrict__ pixrec,
    const __half* __restrict__ t1, const __half* __restrict__ t2,
    const __half* __restrict__ t3, const __half* __restrict__ t4,
    __half* __restrict__ ws2) {
  // 8192 blocks; XCD-chunked swizzle -> 1024-block contiguous chunks.
  int bid = blockIdx.x;
  int swz = (bid & 7) * 1024 + (bid >> 3);
  int g = swz * 256 + threadIdx.x;
  int i = g >> 1;        // pixel slot in bin order
  int h = g & 1;         // channel half (0: ch0-7, 1: ch8-15)
  float4 r = pixrec[i];
  float u = r.x, v = r.y;
  unsigned p = __float_as_uint(r.z);
  float m = r.w;
  // Shared validity from layer1's unclamped indices.
  float fx1 = floorf(u * 1023.0f), fy1 = floorf(v * 1023.0f);
  float vx0 = (fx1 >= 0.0f && fx1 <= 1023.0f) ? 1.0f : 0.0f;
  float vx1 = (fx1 + 1.0f >= 0.0f && fx1 + 1.0f <= 1023.0f) ? 1.0f : 0.0f;
  float vy0 = (fy1 >= 0.0f && fy1 <= 1023.0f) ? 1.0f : 0.0f;
  float vy1 = (fy1 + 1.0f >= 0.0f && fy1 + 1.0f <= 1023.0f) ? 1.0f : 0.0f;
  float c00 = vy0 * vx0, c01 = vy0 * vx1, c10 = vy1 * vx0, c11 = vy1 * vx1;

  const uint4* T[4] = {(const uint4*)t1, (const uint4*)t2,
                       (const uint4*)t3, (const uint4*)t4};
  const int Ws[4] = {1024, 512, 256, 128};
  uint4 A[4][4];
  float wx1s[4], wy1s[4];
#pragma unroll
  for (int L = 0; L < 4; ++L) {
    int W = Ws[L];
    float ix = u * (float)(W - 1);
    float iy = v * (float)(W - 1);
    float fx = floorf(ix), fy = floorf(iy);
    wx1s[L] = ix - fx;
    wy1s[L] = iy - fy;
    int x0 = min(max((int)fx, 0), W - 1);
    int x1 = min(x0 + 1, W - 1);
    int y0 = min(max((int)fy, 0), W - 1);
    int y1 = min(y0 + 1, W - 1);
    const uint4* base = T[L];
    A[L][0] = base[((size_t)y0 * W + x0) * 2 + h];
    A[L][1] = base[((size_t)y0 * W + x1) * 2 + h];
    A[L][2] = base[((size_t)y1 * W + x0) * 2 + h];
    A[L][3] = base[((size_t)y1 * W + x1) * 2 + h];
  }
  float acc[8];
#pragma unroll
  for (int c = 0; c < 8; ++c) acc[c] = 0.0f;
#pragma unroll
  for (int L = 0; L < 4; ++L) {
    float wx1 = wx1s[L], wy1 = wy1s[L];
    float wx0 = 1.0f - wx1, wy0 = 1.0f - wy1;
    __half2 w00h = __float2half2_rn(wy0 * wx0 * c00);
    __half2 w01h = __float2half2_rn(wy0 * wx1 * c01);
    __half2 w10h = __float2half2_rn(wy1 * wx0 * c10);
    __half2 w11h = __float2half2_rn(wy1 * wx1 * c11);
    union { uint4 u4; __half2 hh[4]; } a00, a01, a10, a11;
    a00.u4 = A[L][0]; a01.u4 = A[L][1]; a10.u4 = A[L][2]; a11.u4 = A[L][3];
#pragma unroll
    for (int k = 0; k < 4; ++k) {
      __half2 s = __hmul2(a00.hh[k], w00h);
      s = __hfma2(a01.hh[k], w01h, s);
      s = __hfma2(a10.hh[k], w10h, s);
      s = __hfma2(a11.hh[k], w11h, s);
      float2 f = __half22float2(s);
      acc[2 * k + 0] += f.x;
      acc[2 * k + 1] += f.y;
    }
  }
  union { __half2 hh[4]; uint4 u4; } o;
#pragma unroll
  for (int c = 0; c < 4; ++c)
    o.hh[c] = __floats2half2_rn(acc[2 * c] * m, acc[2 * c + 1] * m);
  ((uint4*)(ws2 + (size_t)p * CH))[h] = o.u4;
}

// Unscatter fp16 ws2[p][16] -> f32 out[B][C][Ho][Wo]. 4 px/thread, NT stores.
__global__ __launch_bounds__(256) void unscatter16_kernel(
    const __half* __restrict__ ws2, float* __restrict__ out) {
  int t = blockIdx.x * blockDim.x + threadIdx.x;  // [0, NPIX/4)
  int p0 = t * 4;
  int wo = p0 & 511, ho = (p0 >> 9) & 511, b = p0 >> 18;
  const uint4* s = (const uint4*)ws2;
  union { uint4 u[2]; __half2 h[8]; } v[4];
#pragma unroll
  for (int j = 0; j < 4; ++j) {
    v[j].u[0] = s[(size_t)(p0 + j) * 2 + 0];
    v[j].u[1] = s[(size_t)(p0 + j) * 2 + 1];
  }
  size_t obase = (size_t)b * (CH * 262144) + (size_t)ho * 512 + wo;
#pragma unroll
  for (int ch = 0; ch < CH; ++ch) {
    vfloat4 o;
    o.x = __half2float(((ch & 1) ? __high2half(v[0].h[ch >> 1]) : __low2half(v[0].h[ch >> 1])));
    o.y = __half2float(((ch & 1) ? __high2half(v[1].h[ch >> 1]) : __low2half(v[1].h[ch >> 1])));
    o.z = __half2float(((ch & 1) ? __high2half(v[2].h[ch >> 1]) : __low2half(v[2].h[ch >> 1])));
    o.w = __half2float(((ch & 1) ? __high2half(v[3].h[ch >> 1]) : __low2half(v[3].h[ch >> 1])));
    __builtin_nontemporal_store(o, (vfloat4*)(out + obase + (size_t)ch * 262144));
  }
}

// ---------------------------------------------------------------------------
// Fallback path kernels (ws too small for the binned pipeline).
// ---------------------------------------------------------------------------
__global__ __launch_bounds__(256) void interleave_lds2_kernel(
    const float* __restrict__ l1, const float* __restrict__ l2,
    const float* __restrict__ l3, const float* __restrict__ l4,
    __half* __restrict__ w1, __half* __restrict__ w2,
    __half* __restrict__ w3, __half* __restrict__ w4) {
  __shared__ unsigned lds_u[CH][258];
  int b = blockIdx.x;
  const float* src; __half* dst; int HW; size_t tb;
  if (b < 2048)      { src = l1; dst = w1; HW = 1048576; tb = (size_t)b * 512; }
  else if (b < 2560) { src = l2; dst = w2; HW = 262144;  tb = (size_t)(b - 2048) * 512; }
  else if (b < 2688) { src = l3; dst = w3; HW = 65536;   tb = (size_t)(b - 2560) * 512; }
  else               { src = l4; dst = w4; HW = 16384;   tb = (size_t)(b - 2688) * 512; }
  int t = threadIdx.x, lane = t & 63, cg = t >> 6;
#pragma unroll
  for (int j = 0; j < 4; ++j) {
    int c = cg * 4 + j;
    const vfloat4* s4 = (const vfloat4*)(src + (size_t)c * HW + tb);
#pragma unroll
    for (int half_ = 0; half_ < 2; ++half_) {
      vfloat4 v = __builtin_nontemporal_load(&s4[half_ * 64 + lane]);
      unsigned h0 = __half_as_ushort(__float2half(v.x));
      unsigned h1 = __half_as_ushort(__float2half(v.y));
      unsigned h2 = __half_as_ushort(__float2half(v.z));
      unsigned h3 = __half_as_ushort(__float2half(v.w));
      lds_u[c][half_ * 128 + lane * 2 + 0] = h0 | (h1 << 16);
      lds_u[c][half_ * 128 + lane * 2 + 1] = h2 | (h3 << 16);
    }
  }
  __syncthreads();
#pragma unroll
  for (int q = 0; q < 2; ++q) {
    int tt = t + q * 256;
    int idx = tt >> 1, sh = (tt & 1) * 16;
    unsigned o[8];
#pragma unroll
    for (int k = 0; k < 8; ++k) {
      unsigned lo = (lds_u[2 * k + 0][idx] >> sh) & 0xffffu;
      unsigned hi = (lds_u[2 * k + 1][idx] >> sh) & 0xffffu;
      o[k] = lo | (hi << 16);
    }
    uint4* d = (uint4*)(dst + (tb + tt) * CH);
    d[0] = make_uint4(o[0], o[1], o[2], o[3]);
    d[1] = make_uint4(o[4], o[5], o[6], o[7]);
  }
}

__device__ __forceinline__ void corner_fma(const __half* __restrict__ t,
                                           size_t texel, float w, float acc[CH]) {
  const uint4* q = (const uint4*)(t + texel * CH);
  union { uint4 u; __half2 h[4]; } a, b;
  a.u = q[0];
  b.u = q[1];
#pragma unroll
  for (int i = 0; i < 4; ++i) {
    float2 f = __half22float2(a.h[i]);
    acc[2 * i + 0] = fmaf(f.x, w, acc[2 * i + 0]);
    acc[2 * i + 1] = fmaf(f.y, w, acc[2 * i + 1]);
  }
#pragma unroll
  for (int i = 0; i < 4; ++i) {
    float2 f = __half22float2(b.h[i]);
    acc[8 + 2 * i + 0] = fmaf(f.x, w, acc[8 + 2 * i + 0]);
    acc[8 + 2 * i + 1] = fmaf(f.y, w, acc[8 + 2 * i + 1]);
  }
}

__device__ __forceinline__ void sample_hwc16(const __half* __restrict__ t, int W,
                                             float gx, float gy, float acc[CH]) {
  const float W1 = (float)(W - 1);
  float ix = (gx + 1.0f) * 0.5f * W1;
  float iy = (gy + 1.0f) * 0.5f * W1;
  float ix0f = floorf(ix), iy0f = floorf(iy);
  float wx1 = ix - ix0f, wy1 = iy - iy0f;
  float wx0 = 1.0f - wx1, wy0 = 1.0f - wy1;
  float ix1f = ix0f + 1.0f, iy1f = iy0f + 1.0f;
  float vx0 = (ix0f >= 0.0f && ix0f <= W1) ? 1.0f : 0.0f;
  float vx1 = (ix1f >= 0.0f && ix1f <= W1) ? 1.0f : 0.0f;
  float vy0 = (iy0f >= 0.0f && iy0f <= W1) ? 1.0f : 0.0f;
  float vy1 = (iy1f >= 0.0f && iy1f <= W1) ? 1.0f : 0.0f;
  int x0 = min(max((int)ix0f, 0), W - 1);
  int x1 = min(max((int)ix1f, 0), W - 1);
  int y0 = min(max((int)iy0f, 0), W - 1);
  int y1 = min(max((int)iy1f, 0), W - 1);
  float w00 = wy0 * wx0 * vy0 * vx0;
  float w01 = wy0 * wx1 * vy0 * vx1;
  float w10 = wy1 * wx0 * vy1 * vx0;
  float w11 = wy1 * wx1 * vy1 * vx1;
  corner_fma(t, (size_t)y0 * W + x0, w00, acc);
  corner_fma(t, (size_t)y0 * W + x1, w01, acc);
  corner_fma(t, (size_t)y1 * W + x0, w10, acc);
  corner_fma(t, (size_t)y1 * W + x1, w11, acc);
}

__global__ __launch_bounds__(256) void gather_hwc16_kernel(
    const float* __restrict__ x, const float* __restrict__ msk,
    const __half* __restrict__ t1, const __half* __restrict__ t2,
    const __half* __restrict__ t3, const __half* __restrict__ t4,
    float* __restrict__ out) {
  int p = blockIdx.x * blockDim.x + threadIdx.x;
  int wo = p & 511, ho = (p >> 9) & 511, b = p >> 18;
  float2 g = ((const float2*)x)[p];
  float gx = g.x * 2.0f - 1.0f;
  float gy = g.y * 2.0f - 1.0f;
  float m = msk[p];
  float acc[CH];
#pragma unroll
  for (int c = 0; c < CH; ++c) acc[c] = 0.0f;
  sample_hwc16(t1, 1024, gx, gy, acc);
  sample_hwc16(t2, 512, gx, gy, acc);
  sample_hwc16(t3, 256, gx, gy, acc);
  sample_hwc16(t4, 128, gx, gy, acc);
  size_t obase = (size_t)b * (CH * 262144) + (size_t)ho * 512 + wo;
#pragma unroll
  for (int c = 0; c < CH; ++c) out[obase + (size_t)c * 262144] = acc[c] * m;
}

__device__ __forceinline__ void sample_chw(const float* __restrict__ t, int W,
                                           float gx, float gy, float acc[CH]) {
  const float W1 = (float)(W - 1);
  float ix = (gx + 1.0f) * 0.5f * W1;
  float iy = (gy + 1.0f) * 0.5f * W1;
  float ix0f = floorf(ix), iy0f = floorf(iy);
  float wx1 = ix - ix0f, wy1 = iy - iy0f;
  float wx0 = 1.0f - wx1, wy0 = 1.0f - wy1;
  float ix1f = ix0f + 1.0f, iy1f = iy0f + 1.0f;
  float vx0 = (ix0f >= 0.0f && ix0f <= W1) ? 1.0f : 0.0f;
  float vx1 = (ix1f >= 0.0f && ix1f <= W1) ? 1.0f : 0.0f;
  float vy0 = (iy0f >= 0.0f && iy0f <= W1) ? 1.0f : 0.0f;
  float vy1 = (iy1f >= 0.0f && iy1f <= W1) ? 1.0f : 0.0f;
  int x0 = min(max((int)ix0f, 0), W - 1);
  int x1 = min(max((int)ix1f, 0), W - 1);
  int y0 = min(max((int)iy0f, 0), W - 1);
  int y1 = min(max((int)iy1f, 0), W - 1);
  float w00 = wy0 * wx0 * vy0 * vx0;
  float w01 = wy0 * wx1 * vy0 * vx1;
  float w10 = wy1 * wx0 * vy1 * vx0;
  float w11 = wy1 * wx1 * vy1 * vx1;
  size_t HW = (size_t)W * W;
  const float* b00 = t + (size_t)y0 * W + x0;
  const float* b01 = t + (size_t)y0 * W + x1;
  const float* b10 = t + (size_t)y1 * W + x0;
  const float* b11 = t + (size_t)y1 * W + x1;
#pragma unroll
  for (int c = 0; c < CH; ++c) {
    float v00 = b00[c * HW], v01 = b01[c * HW], v10 = b10[c * HW], v11 = b11[c * HW];
    acc[c] = fmaf(v00, w00, fmaf(v01, w01, fmaf(v10, w10, fmaf(v11, w11, acc[c]))));
  }
}

__global__ __launch_bounds__(256) void gather_chw_kernel(
    const float* __restrict__ x, const float* __restrict__ msk,
    const float* __restrict__ l1, const float* __restrict__ l2,
    const float* __restrict__ l3, const float* __restrict__ l4,
    float* __restrict__ out) {
  int p = blockIdx.x * blockDim.x + threadIdx.x;
  int wo = p & 511, ho = (p >> 9) & 511, b = p >> 18;
  float2 g = ((const float2*)x)[p];
  float gx = g.x * 2.0f - 1.0f;
  float gy = g.y * 2.0f - 1.0f;
  float m = msk[p];
  float acc[CH];
#pragma unroll
  for (int c = 0; c < CH; ++c) acc[c] = 0.0f;
  sample_chw(l1, 1024, gx, gy, acc);
  sample_chw(l2, 512, gx, gy, acc);
  sample_chw(l3, 256, gx, gy, acc);
  sample_chw(l4, 128, gx, gy, acc);
  size_t obase = (size_t)b * (CH * 262144) + (size_t)ho * 512 + wo;
#pragma unroll
  for (int c = 0; c < CH; ++c) out[obase + (size_t)c * 262144] = acc[c] * m;
}

extern "C" void kernel_launch(void* const* d_in, const int* in_sizes, int n_in,
                              void* d_out, int out_size, void* d_ws, size_t ws_size,
                              hipStream_t stream) {
  const float* x   = (const float*)d_in[0];
  const float* msk = (const float*)d_in[1];
  const float* l1  = (const float*)d_in[2];
  const float* l2  = (const float*)d_in[3];
  const float* l3  = (const float*)d_in[4];
  const float* l4  = (const float*)d_in[5];
  float* out = (float*)d_out;

  const size_t n_texel = 1048576 + 262144 + 65536 + 16384;      // 1392640
  const size_t tex_bytes = n_texel * CH * sizeof(__half);        // ~44.6 MB
  const size_t ws2_bytes = (size_t)NPIX * CH * sizeof(__half);   // 32 MB
  const size_t rec_bytes = (size_t)NPIX * sizeof(float4);        // 16 MB
  const size_t need_bin  = ws2_bytes + tex_bytes + rec_bytes;
  const size_t need_f16  = tex_bytes;

  if (ws_size >= need_bin) {
    char* base = (char*)d_ws;
    __half* ws2    = (__half*)base;
    __half* w1     = (__half*)(base + ws2_bytes);
    __half* w2     = w1 + (size_t)1048576 * CH;
    __half* w3     = w2 + (size_t)262144 * CH;
    __half* w4     = w3 + (size_t)65536 * CH;
    float4* pixrec = (float4*)(base + ws2_bytes + tex_bytes);
    // Sort metadata aliases into ws2 (dead once gather starts writing ws2):
    unsigned* hist    = (unsigned*)base;                          // 4 MB
    unsigned* totals  = hist + (size_t)NBLK_SORT * NBINS;         // 16 KB
    unsigned* binbase = totals + NBINS;                           // 16 KB

    ilv_hist_kernel<<<NILV + NBLK_SORT, 256, 0, stream>>>(
        l1, l2, l3, l4, w1, w2, w3, w4, (const float2*)x, hist);
    colscan2_kernel<<<NBINS / 256, 256, 0, stream>>>(hist, totals);
    scan_kernel<<<1, 1024, 0, stream>>>(totals, binbase);
    scatter2_kernel<<<NBLK_SORT, 256, 0, stream>>>(
        (const float2*)x, msk, hist, binbase, pixrec);
    gather_binned6_kernel<<<NPIX * 2 / 256, 256, 0, stream>>>(
        pixrec, w1, w2, w3, w4, ws2);
    unscatter16_kernel<<<NPIX / 4 / 256, 256, 0, stream>>>(ws2, out);
  } else if (ws_size >= need_f16) {
    __half* w1 = (__half*)d_ws;
    __half* w2 = w1 + (size_t)1048576 * CH;
    __half* w3 = w2 + (size_t)262144 * CH;
    __half* w4 = w3 + (size_t)65536 * CH;
    interleave_lds2_kernel<<<(int)(n_texel / 512), 256, 0, stream>>>(
        l1, l2, l3, l4, w1, w2, w3, w4);
    gather_hwc16_kernel<<<NPIX / 256, 256, 0, stream>>>(x, msk, w1, w2, w3, w4, out);
  } else {
    gather_chw_kernel<<<NPIX / 256, 256, 0, stream>>>(x, msk, l1, l2, l3, l4, out);
  }
}